// Round 14
// baseline (326.834 us; speedup 1.0000x reference)
//
#include <hip/hip_runtime.h>
#include <hip/hip_bf16.h>

#define H_ 128
#define W_ 128
#define HW_ 16384
#define B_ 16
#define IW_ 130   // padded spatial dim

using short8 = __attribute__((ext_vector_type(8))) short;
using f32x4  = __attribute__((ext_vector_type(4))) float;

__device__ __forceinline__ unsigned short f2b(float v) {
    __hip_bfloat16 h = __float2bfloat16(v);
    return *reinterpret_cast<unsigned short*>(&h);
}
__device__ __forceinline__ float b2f(unsigned short u) {
    __hip_bfloat16 h = *reinterpret_cast<__hip_bfloat16*>(&u);
    return __bfloat162float(h);
}

// ---------------------------------------------------------------------------
// Zero the 1-px border of a padded NHWC tensor [B][130][130][C8c*8] bf16.
// Runs every call (ws is re-poisoned 0xAA before each timed launch).
// ---------------------------------------------------------------------------
__global__ __launch_bounds__(256) void zero_pad(unsigned short* __restrict__ p, int C8c)
{
    int i = blockIdx.x * 256 + threadIdx.x;
    int per = 516 * C8c;                   // border positions per image * chunks
    int total = B_ * per;
    if (i >= total) return;
    int b = i / per, r = i % per;
    int pos = r / C8c, k = r % C8c;
    int y, x;
    if (pos < 130)      { y = 0;         x = pos; }
    else if (pos < 260) { y = 129;       x = pos - 130; }
    else if (pos < 388) { y = pos - 259; x = 0; }      // y = 1..128
    else                { y = pos - 387; x = 129; }    // y = 1..128
    short8 z = {};
    *reinterpret_cast<short8*>(p + (((size_t)(b * IW_ + y) * IW_ + x) * C8c + k) * 8) = z;
}

// ---------------------------------------------------------------------------
// x [B][32][H][W] f32  ->  xc_pad [B][130][130][32] bf16 (interior)
// ---------------------------------------------------------------------------
__global__ __launch_bounds__(256) void to_nhwc(
    const float* __restrict__ x, unsigned short* __restrict__ xc)
{
    int p = blockIdx.x * 256 + threadIdx.x;           // 0 .. B*HW-1
    int b = p >> 14, rem = p & 16383;
    int yy = rem >> 7, xx = rem & 127;
    const float* src = x + (size_t)b * 32 * HW_ + rem;
    unsigned short ob[32];
    #pragma unroll
    for (int c = 0; c < 32; ++c) ob[c] = f2b(src[(size_t)c * HW_]);
    unsigned short* dst = xc + ((size_t)(b * IW_ + yy + 1) * IW_ + xx + 1) * 32;
    #pragma unroll
    for (int k = 0; k < 4; ++k)
        *reinterpret_cast<short8*>(dst + k * 8) = *reinterpret_cast<short8*>(&ob[k * 8]);
}

// ---------------------------------------------------------------------------
// w [co<63][CIN][KS][KS] f32 -> wt [tap][cb][kb(4)][co(64)][j(8)] bf16
// ---------------------------------------------------------------------------
__global__ __launch_bounds__(256) void prep_w(
    const float* __restrict__ w, unsigned short* __restrict__ wt, int CIN, int KS)
{
    int NCB = CIN >> 5;
    int total = KS * KS * NCB * 4 * 64 * 8;
    for (int i = blockIdx.x * 256 + threadIdx.x; i < total; i += gridDim.x * 256) {
        int j  = i & 7;
        int co = (i >> 3) & 63;
        int kb = (i >> 9) & 3;
        int cb = (i >> 11) % NCB;
        int tap = (i >> 11) / NCB;
        int ky = tap / KS, kx = tap % KS;
        int ci = cb * 32 + kb * 8 + j;
        float v = (co < 63) ? w[((co * CIN + ci) * KS + ky) * KS + kx] : 0.f;
        wt[i] = f2b(v);
    }
}

// ---------------------------------------------------------------------------
// Implicit-GEMM conv, direct-global A operand (padded NHWC input), weights in
// LDS. Rounds 12-13 proved the bulk-sync LDS-ring insensitive to TLP and ILP
// (m233 2-phase stall signature); here the K-loop has NO barriers and no LDS
// A-path: per iter 4 independent global 16B A-loads (dense 2KB/wave window,
// L1/L2-cached, 9x tap reuse) + 4 LDS B-reads + 16 MFMA.
// Block = 256 thr = 4 waves: (row rsub, px half) -> each wave 64px x 64co on
// one of 2 output rows. Grid = B*H/2.
// BN stats: q-shfl reduce -> LDS block reduce -> 128 atomics/block.
// MFMA mapping (m89/m91): A lane l -> row l&15, k-oct l>>4; B lane l ->
// col l&15, k-oct l>>4; D lane l -> col l&15, row 4*(l>>4)+reg.
// ---------------------------------------------------------------------------
template<int CIN, int KS>
__global__ __launch_bounds__(256) void conv_mfma(
    const unsigned short* __restrict__ inp,  // PADDED NHWC bf16 [B][130][130][CIN]
    const unsigned short* __restrict__ wt,   // packed weights
    unsigned short* __restrict__ outp,       // NHWC bf16 [B][H][W][64]
    float* __restrict__ sums)                // [0..63]=sum, [64..127]=sumsq
{
    constexpr int NCB  = CIN / 32;
    constexpr int TAPS = KS * KS;
    constexpr int NK   = TAPS * NCB;
    constexpr int C8   = CIN / 8;
    constexpr int RO   = (KS == 1) ? 1 : 0;  // 1x1 reads interior directly
    constexpr int WCH  = NK * 256;

    __shared__ short8 wl[WCH];
    __shared__ float red[4][2][64];

    const int bid = blockIdx.x;
    const int b  = bid >> 6;
    const int y0 = (bid & 63) * 2;
    const int t  = threadIdx.x;
    const int lane = t & 63;
    const int wv = t >> 6;                  // 0..3
    const int rsub = wv >> 1;               // output row within block
    const int xbase = (wv & 1) * 64;        // px half
    const int l15 = lane & 15;
    const int q = lane >> 4;
    const int y = y0 + rsub;

    const short8* in8 = reinterpret_cast<const short8*>(inp);
    const short8* wt8 = reinterpret_cast<const short8*>(wt);

    for (int i = t; i < WCH; i += 256) wl[i] = wt8[i];
    __syncthreads();

    // per-lane base chunk: (row y+RO, col xbase+l15+RO, chunk q)
    const size_t lanebase =
        ((size_t)(b * IW_ + y + RO) * IW_ + xbase + l15 + RO) * C8 + q;

    f32x4 acc[4][4];                        // [f(16px)][cf(16co)]
    #pragma unroll
    for (int f = 0; f < 4; ++f)
        #pragma unroll
        for (int cf = 0; cf < 4; ++cf)
            #pragma unroll
            for (int r = 0; r < 4; ++r) acc[f][cf][r] = 0.f;

    #pragma unroll
    for (int tap = 0; tap < TAPS; ++tap) {
        const int ky = tap / KS, kx = tap % KS;
        #pragma unroll
        for (int cb = 0; cb < NCB; ++cb) {
            const int tc = tap * NCB + cb;
            short8 bf[4];
            #pragma unroll
            for (int cf = 0; cf < 4; ++cf)
                bf[cf] = wl[(tc * 4 + q) * 64 + cf * 16 + l15];
            short8 af[4];
            #pragma unroll
            for (int f = 0; f < 4; ++f)
                af[f] = in8[lanebase + ((size_t)ky * IW_ + kx + f * 16) * C8 + cb * 4];
            #pragma unroll
            for (int f = 0; f < 4; ++f)
                #pragma unroll
                for (int cf = 0; cf < 4; ++cf)
                    acc[f][cf] = __builtin_amdgcn_mfma_f32_16x16x32_bf16(
                        af[f], bf[cf], acc[f][cf], 0, 0, 0);
        }
    }

    // ---- store (bf16 NHWC) + BN partial stats ----
    float sacc[4] = {0.f, 0.f, 0.f, 0.f}, qacc[4] = {0.f, 0.f, 0.f, 0.f};
    const size_t obase = ((size_t)(b * H_ + y) * W_) * 64;
    #pragma unroll
    for (int f = 0; f < 4; ++f)
        #pragma unroll
        for (int cf = 0; cf < 4; ++cf)
            #pragma unroll
            for (int r = 0; r < 4; ++r) {
                float v = acc[f][cf][r];
                int x = xbase + f * 16 + q * 4 + r;
                int co = cf * 16 + l15;
                outp[obase + (size_t)x * 64 + co] = f2b(v);
                sacc[cf] += v;
                qacc[cf] = fmaf(v, v, qacc[cf]);
            }
    #pragma unroll
    for (int cf = 0; cf < 4; ++cf) {
        float s = sacc[cf], qq = qacc[cf];
        s += __shfl_xor(s, 16); qq += __shfl_xor(qq, 16);
        s += __shfl_xor(s, 32); qq += __shfl_xor(qq, 32);
        if (q == 0) {
            red[wv][0][cf * 16 + l15] = s;
            red[wv][1][cf * 16 + l15] = qq;
        }
    }
    __syncthreads();
    if (t < 128) {
        int co = t & 63, cnt = t >> 6;
        float v = red[0][cnt][co] + red[1][cnt][co] + red[2][cnt][co] + red[3][cnt][co];
        atomicAdd(&sums[cnt * 64 + co], v);
    }
}

// ---------------------------------------------------------------------------
__global__ void finalize_stats(const float* __restrict__ sums, float* __restrict__ murs)
{
    int set = blockIdx.x, c = threadIdx.x;
    const float invN = 1.f / (16.f * 16384.f);
    float s = sums[set * 128 + c];
    float qv = sums[set * 128 + 64 + c];
    float mu = s * invN;
    float var = qv * invN - mu * mu;
    murs[set * 128 + c] = mu;
    murs[set * 128 + 64 + c] = rsqrtf(fmaxf(var, 0.f) + 1e-5f);
}

// ---------------------------------------------------------------------------
// h_pad interior = project(relu(BN(s1)))  (padded NHWC bf16, ch0 = time)
// ---------------------------------------------------------------------------
__global__ __launch_bounds__(256) void epi1(
    const unsigned short* __restrict__ s1, const float* __restrict__ murs,
    const float* __restrict__ g, const float* __restrict__ bt,
    unsigned short* __restrict__ h)
{
    int p = blockIdx.x * 256 + threadIdx.x;
    int b = p >> 14, rem = p & 16383;
    int yy = rem >> 7, xx = rem & 127;
    const unsigned short* sp = s1 + (size_t)p * 64;
    unsigned short ib[64], ob[64];
    #pragma unroll
    for (int k = 0; k < 8; ++k)
        *reinterpret_cast<short8*>(&ib[k * 8]) = *reinterpret_cast<const short8*>(sp + k * 8);
    float ssq = 0.f;
    #pragma unroll
    for (int c = 0; c < 63; ++c) {
        float v = b2f(ib[c]);
        v = g[c] * ((v - murs[c]) * murs[64 + c]) + bt[c];
        v = fmaxf(v, 0.f);
        ssq = fmaf(v, v, ssq);
        ob[c + 1] = f2b(v);
    }
    ob[0] = f2b(sqrtf(1.f + ssq));
    unsigned short* hp = h + ((size_t)(b * IW_ + yy + 1) * IW_ + xx + 1) * 64;
    #pragma unroll
    for (int k = 0; k < 8; ++k)
        *reinterpret_cast<short8*>(hp + k * 8) = *reinterpret_cast<short8*>(&ob[k * 8]);
}

// ---------------------------------------------------------------------------
// out = project(relu(BN(s2) + BN(sp)))  -> f32 NCHW (ch0 = time)
// ---------------------------------------------------------------------------
__global__ __launch_bounds__(256) void epi2(
    const unsigned short* __restrict__ s2, const unsigned short* __restrict__ spb,
    const float* __restrict__ murs2, const float* __restrict__ mursp,
    const float* __restrict__ g2, const float* __restrict__ bt2,
    const float* __restrict__ gp, const float* __restrict__ btp,
    float* __restrict__ out)
{
    int p = blockIdx.x * 256 + threadIdx.x;
    int b = p >> 14, rem = p & 16383;
    unsigned short i2[64], ip[64];
    #pragma unroll
    for (int k = 0; k < 8; ++k) {
        *reinterpret_cast<short8*>(&i2[k * 8]) =
            *reinterpret_cast<const short8*>(s2 + (size_t)p * 64 + k * 8);
        *reinterpret_cast<short8*>(&ip[k * 8]) =
            *reinterpret_cast<const short8*>(spb + (size_t)p * 64 + k * 8);
    }
    float* ob = out + (size_t)b * 64 * HW_ + rem;
    float ssq = 0.f;
    #pragma unroll
    for (int c = 0; c < 63; ++c) {
        float v2 = b2f(i2[c]);
        v2 = g2[c] * ((v2 - murs2[c]) * murs2[64 + c]) + bt2[c];
        float vp = b2f(ip[c]);
        vp = gp[c] * ((vp - mursp[c]) * mursp[64 + c]) + btp[c];
        float r = fmaxf(v2 + vp, 0.f);
        ssq = fmaf(r, r, ssq);
        ob[(size_t)(c + 1) * HW_] = r;
    }
    ob[0] = sqrtf(1.f + ssq);
}

// ---------------------------------------------------------------------------
extern "C" void kernel_launch(void* const* d_in, const int* in_sizes, int n_in,
                              void* d_out, int out_size, void* d_ws, size_t ws_size,
                              hipStream_t stream)
{
    (void)in_sizes; (void)n_in; (void)out_size; (void)ws_size;
    const float* x   = (const float*)d_in[0];
    const float* w1  = (const float*)d_in[1];
    const float* g1  = (const float*)d_in[3];
    const float* bt1 = (const float*)d_in[4];
    const float* w2  = (const float*)d_in[5];
    const float* g2  = (const float*)d_in[7];
    const float* bt2 = (const float*)d_in[8];
    const float* wp  = (const float*)d_in[9];
    const float* gp  = (const float*)d_in[11];
    const float* btp = (const float*)d_in[12];
    // biases b1/b2/bp are mathematically dead: BN immediately follows each conv.
    float* out = (float*)d_out;
    char* ws = (char*)d_ws;

    // ws layout (bytes)
    unsigned short* xcp = (unsigned short*)(ws);                 // 17,305,600 B padded NHWC32
    unsigned short* s1  = (unsigned short*)(ws + 17305600);      // 33,554,432 B (reused as sp)
    unsigned short* hp  = (unsigned short*)(ws + 50860032);      // 34,611,200 B padded NHWC64
    unsigned short* s2  = (unsigned short*)(ws + 85471232);      // 33,554,432 B
    unsigned short* w1t = (unsigned short*)(ws + 119025664);     //     36,864 B
    unsigned short* w2t = (unsigned short*)(ws + 119062528);     //     73,728 B
    unsigned short* wpt = (unsigned short*)(ws + 119136256);     //      4,096 B
    float* sums = (float*)(ws + 119140352);                      //      1,536 B
    float* murs = (float*)(ws + 119141888);                      //      1,536 B

    hipMemsetAsync(sums, 0, 1536, stream);
    zero_pad<<<129, 256, 0, stream>>>(xcp, 4);    // 16*516*4 = 33024 threads
    zero_pad<<<258, 256, 0, stream>>>(hp, 8);     // 16*516*8 = 66048 threads
    to_nhwc<<<1024, 256, 0, stream>>>(x, xcp);
    prep_w<<<72, 256, 0, stream>>>(w1, w1t, 32, 3);
    prep_w<<<144, 256, 0, stream>>>(w2, w2t, 64, 3);
    prep_w<<<8, 256, 0, stream>>>(wp, wpt, 32, 1);

    conv_mfma<32, 3><<<1024, 256, 0, stream>>>(xcp, w1t, s1, sums);
    finalize_stats<<<1, 64, 0, stream>>>(sums, murs);
    epi1<<<1024, 256, 0, stream>>>(s1, murs, g1, bt1, hp);
    conv_mfma<64, 3><<<1024, 256, 0, stream>>>(hp, w2t, s2, sums + 128);
    conv_mfma<32, 1><<<1024, 256, 0, stream>>>(xcp, wpt, s1, sums + 256);  // sp reuses s1
    finalize_stats<<<2, 64, 0, stream>>>(sums + 128, murs + 128);
    epi2<<<1024, 256, 0, stream>>>(s2, s1, murs + 128, murs + 256,
                                   g2, bt2, gp, btp, out);
}